// Round 20
// baseline (110.200 us; speedup 1.0000x reference)
//
#include <hip/hip_runtime.h>
#include <cstdint>

#define GC 32768
#define GN (2*GC)
#define GE (3*GC-2)
#define NSTRIP 1024

typedef _Float16 f16x8 __attribute__((ext_vector_type(8)));
typedef float f32x4 __attribute__((ext_vector_type(4)));

// ---- unified G1 weight mapping (R6-R19-proven) ----
// feature space (F per-node feats): [dst_h0(F) dst_h1(F) src_h0(F) src_h1(F) e1(4) e2(4) e3(4)]
// N space: [A(H) B(H) V(H)]
__device__ __forceinline__ float g1w(const float* w1, int F, int H, int f, int n) {
    if (n >= 3 * H) return 0.f;
    int t = n / H, h = n % H;
    const float* w = w1 + h * (2 * F + 4);
    if (t == 0) {
        if (f < F) return w[f];
        if (f >= 2*F && f < 3*F) return w[F + f - 2*F];
        if (f >= 4*F && f < 4*F + 4) return w[2*F + f - 4*F];
    } else if (t == 1) {
        if (f >= F && f < 2*F) return w[f - F];
        if (f >= 3*F && f < 4*F) return w[F + f - 3*F];
        if (f >= 4*F + 4 && f < 4*F + 8) return w[2*F + f - (4*F+4)];
    } else {
        if (f < F) return w[F + f];
        if (f >= F && f < 2*F) return w[f - F];
        if (f >= 4*F + 8 && f < 4*F + 12) return w[2*F + f - (4*F+8)];
    }
    return 0.f;
}

__device__ __forceinline__ uint32_t pkf16(float a, float b) {
    unsigned short ua = __builtin_bit_cast(unsigned short, (_Float16)a);
    unsigned short ub = __builtin_bit_cast(unsigned short, (_Float16)b);
    return (uint32_t)ua | ((uint32_t)ub << 16);
}
__device__ __forceinline__ uint32_t splitpk(float v) {
    _Float16 h = (_Float16)v;
    _Float16 lo = (_Float16)(v - (float)h);
    return (uint32_t)__builtin_bit_cast(unsigned short, h) |
           ((uint32_t)__builtin_bit_cast(unsigned short, lo) << 16);
}
template<int CTRL>
__device__ __forceinline__ float dppadd(float v) {
    int s = __builtin_amdgcn_update_dpp(0, __builtin_bit_cast(int, v),
                                        CTRL, 0xF, 0xF, true);
    return v + __builtin_bit_cast(float, s);
}

// 7 fragments (e is PLAIN f16 everywhere; x split; h/z plain):
// 0: L1G1  K0-15 x-split (feat kin>>1), K16-27 e-plain (feat kin-8)
// 1: L1G2  K0-3 plain w1b
// 2,3: L2G1 nt0/nt1  K0-27 plain g1w features (h 0-15, e 16-27)
// 4: L2G2  K0-7 plain w2b
// 5: L3G1  K0-19 = w3a row [dst8 src8 e4]
// 6: L3G2  K0-15 plain w3b
__global__ void build_frags(const float* __restrict__ w1a, const float* __restrict__ w1b,
                            const float* __restrict__ w2a, const float* __restrict__ w2b,
                            const float* __restrict__ w3a, const float* __restrict__ w3b,
                            uint4* __restrict__ tab) {
    int tid = blockIdx.x * 256 + threadIdx.x;
    if (tid >= 7 * 64) return;
    int fr = tid >> 6, l = tid & 63;
    int col = l & 15, kq = l >> 4;
    float v[8];
#pragma unroll
    for (int i = 0; i < 8; ++i) {
        int kin = kq * 8 + i;
        float val = 0.f;
        if (fr == 0) {
            if (kin < 16)      val = g1w(w1a, 2, 4, kin >> 1, col);
            else if (kin < 28) val = g1w(w1a, 2, 4, kin - 8, col);
        }
        else if (fr == 1) val = (kin < 4 && col < 4) ? w1b[col * 4 + kin] : 0.f;
        else if (fr < 4)  val = (kin < 28) ? g1w(w2a, 4, 8, kin, (fr - 2) * 16 + col) : 0.f;
        else if (fr == 4) val = (kin < 8 && col < 8) ? w2b[col * 8 + kin] : 0.f;
        else if (fr == 5) val = (kin < 20) ? w3a[col * 20 + kin] : 0.f;
        else              val = (kin < 16) ? w3b[col * 16 + kin] : 0.f;
        v[i] = val;
    }
    uint4 o;
    o.x = pkf16(v[0], v[1]); o.y = pkf16(v[2], v[3]);
    o.z = pkf16(v[4], v[5]); o.w = pkf16(v[6], v[7]);
    tab[fr * 64 + l] = o;
}

// LDS row layout (bytes):
// E  0..63   2 parity x 32 PLAIN [e1(8) e2(8) e3(8) pad(8)]
// X  64..95  2 parity x 16 split [x0c x1c]
// H2 96..127 2 parity x 16 PLAIN [h0(8) h1(8)]
// H3 128..191 2 parity x 32 PLAIN [h0(16) h1(16)]
// Z1 192..239 3 types x 16 (f16 at 0..7, rest zero)
// Z2 240..287 [t0: zA(16) zB(16) | t1: zV(16)]
// Z3 288..383 3 x 32
#define OFF_E   0
#define OFF_X   64
#define OFF_H2  96
#define OFF_H3  128
#define OFF_Z1  192
#define OFF_Z2  240
#define OFF_Z3  288
#define ROWB    400
#define OUTSTRIDE 132
#define OUTWAVE   (16*OUTSTRIDE)

__device__ __forceinline__ f32x4 mfma16(uint4 a, uint4 b, f32x4 c) {
    return __builtin_amdgcn_mfma_f32_16x16x32_f16(
        __builtin_bit_cast(f16x8, a), __builtin_bit_cast(f16x8, b), c, 0, 0, 0);
}

#define PR4(r) _Pragma("unroll") for (int r = 0; r < 4; ++r)

// One pipeline step. FIRST=false folds jpos selects (1023/1024 blocks).
#define BODY(C, P, W, DO_L12, DO_L3, DO_CMT) do {                                  \
    const int itv = 4*(W) + (C);                                                   \
    if (DO_L3) {                                                                   \
        const bool jp3 = FIRST ? ((j0 + itv - 3) >= 1) : true;                     \
        f32x4 s0 = mfma16(*(const uint4*)rL3[0][P], BF[5], zero);                  \
        f32x4 s1 = mfma16(*(const uint4*)rL3[1][P], BF[5], zero);                  \
        f32x4 s2 = mfma16(*(const uint4*)rL3[2][P], BF[5], zero);                  \
        PR4(r) { *(_Float16*)(wZ3 +  0 + r*ROWB) = (_Float16)fmaxf(s0[r]+zb3,0.f); \
                 *(_Float16*)(wZ3 + 32 + r*ROWB) = (_Float16)fmaxf(s1[r]+zb3,0.f); \
                 *(_Float16*)(wZ3 + 64 + r*ROWB) = (_Float16)fmaxf(s2[r]+zb3,0.f); }\
        f32x4 g0 = mfma16(*(const uint4*)rZ3t[0], BF[6], zero);                    \
        f32x4 g1 = mfma16(*(const uint4*)rZ3t[1], BF[6], zero);                    \
        f32x4 g2 = mfma16(*(const uint4*)rZ3t[2], BF[6], zero);                    \
        float part[4];                                                             \
        PR4(r) { float h0 = jp3 ? g0[r] + cb3 : 0.f;                               \
                 float h1 = (jp3 ? fmaxf(g1[r], g2[r]) : g2[r]) + cb3;             \
                 part[r] = fmaf(h0, wm0, h1 * wm1); }                              \
        PR4(r) { part[r] = dppadd<0xB1>(part[r]);                                  \
                 part[r] = dppadd<0x4E>(part[r]);                                  \
                 part[r] = dppadd<0x141>(part[r]);                                 \
                 part[r] = dppadd<0x140>(part[r]); }                               \
        if (n < 4) {                                                               \
            float v = part[0];                                                     \
            v = (n == 1) ? part[1] : v;                                            \
            v = (n == 2) ? part[2] : v;                                            \
            v = (n == 3) ? part[3] : v;                                            \
            *(float*)(outw + (itv - 3) * 4) = v + bm;                              \
        }                                                                          \
    }                                                                              \
    if (DO_L12) {                                                                  \
        const bool jp = FIRST ? ((j0 + itv - 2) >= 1) : true;                      \
        uint4 a0 = *(const uint4*)rL1[P];                                          \
        f32x4 d1 = mfma16(a0, BF[0], zero);                                        \
        if (n < 12) { PR4(r) *(_Float16*)(wZ1t + r*ROWB) =                         \
                          (_Float16)fmaxf(d1[r] + zb1, 0.f); }                     \
        f32x4 dt0 = mfma16(*(const uint4*)(rZ1 +  0), BF[1], zero);                \
        f32x4 dt1 = mfma16(*(const uint4*)(rZ1 + 16), BF[1], zero);                \
        f32x4 dt2 = mfma16(*(const uint4*)(rZ1 + 32), BF[1], zero);                \
        if (n < 4) { PR4(r) {                                                      \
            float h0 = jp ? dt0[r] + cb1 : 0.f;                                    \
            float h1 = (jp ? fmaxf(dt1[r], dt2[r]) : dt2[r]) + cb1;                \
            *(_Float16*)(wH2p[P] + r*ROWB)     = (_Float16)h0;                     \
            *(_Float16*)(wH2p[P] + 8 + r*ROWB) = (_Float16)h1; } }                 \
        uint4 b0 = *(const uint4*)rL2[P];                                          \
        f32x4 t0 = mfma16(b0, BF[2], zero);                                        \
        f32x4 t1 = mfma16(b0, BF[3], zero);                                        \
        PR4(r) *(_Float16*)(wZ2n + r*ROWB) = (_Float16)fmaxf(t0[r] + zb2, 0.f);    \
        if (n < 8) { PR4(r) *(_Float16*)(wZ2n + 32 + r*ROWB) =                     \
                         (_Float16)fmaxf(t1[r] + zb2, 0.f); }                      \
        f32x4 u0 = mfma16(*(const uint4*)rZ2r[0], BF[4], zero);                    \
        f32x4 u1 = mfma16(*(const uint4*)rZ2r[1], BF[4], zero);                    \
        f32x4 u2 = mfma16(*(const uint4*)rZ2r[2], BF[4], zero);                    \
        if (n < 8) { PR4(r) {                                                      \
            float h0 = jp ? u0[r] + cb2 : 0.f;                                     \
            float h1 = (jp ? fmaxf(u1[r], u2[r]) : u2[r]) + cb2;                   \
            *(_Float16*)(wH3p[P] + r*ROWB)      = (_Float16)h0;                    \
            *(_Float16*)(wH3p[P] + 16 + r*ROWB) = (_Float16)h1; } }                \
    }                                                                              \
    if (DO_CMT) {                                                                  \
        float4 val;                                                                \
        if (q < 3) val = ck[C];                                                    \
        else val = make_float4(                                                    \
            ((C)&1) ? ck[(C)>>1].z     : ck[(C)>>1].x,                             \
            ((C)&1) ? ck[(C)>>1].w     : ck[(C)>>1].y,                             \
            ((C)&1) ? ck[2+((C)>>1)].z : ck[2+((C)>>1)].x,                         \
            ((C)&1) ? ck[2+((C)>>1)].w : ck[2+((C)>>1)].y );                       \
        if (q < 3) {                                                               \
            uint2 o2; o2.x = pkf16(val.x, val.y); o2.y = pkf16(val.z, val.w);      \
            *(uint2*)cmtE[P] = o2;                                                 \
        } else {                                                                   \
            uint4 o; o.x = splitpk(val.x); o.y = splitpk(val.y);                   \
            o.z = splitpk(val.z); o.w = splitpk(val.w);                            \
            *(uint4*)cmtX[P] = o;                                                  \
        }                                                                          \
    }                                                                              \
} while (0)

template<bool FIRST>
__device__ __forceinline__ void mfma_body(
    const float* __restrict__ x, const float* __restrict__ e,
    const float* __restrict__ b1a, const float* __restrict__ b1b,
    const float* __restrict__ b2a, const float* __restrict__ b2b,
    const float* __restrict__ b3a, const float* __restrict__ b3b,
    const float* __restrict__ wmu, const float* __restrict__ bmu,
    const uint4* __restrict__ tab, float* __restrict__ out,
    char* smem, int strip)
{
    const int l  = threadIdx.x & 63;
    const int wv = threadIdx.x >> 6;
    char* wbase  = smem + wv * 16 * ROWB;
    char* ldsout = smem + 4 * 16 * ROWB + wv * OUTWAVE;

    const int bg = wv;
    const int j0 = strip * 32;

    const int n = l & 15;
    const int q = l >> 4;

    { // zero wave-private compute slice (16 x 400 B = 1600 dwords)
        uint32_t* p = (uint32_t*)wbase;
#pragma unroll
        for (int i = 0; i < 25; ++i) p[l * 25 + i] = 0u;
    }

    uint4 BF[7];
#pragma unroll
    for (int f = 0; f < 7; ++f) BF[f] = tab[f * 64 + l];

    const float zb1 = b1a[n & 3], zb2 = b2a[n & 7], zb3 = b3a[n];
    const float cb1 = b1b[n & 3], cb2 = b2b[n & 7], cb3 = b3b[n];
    const float wm0 = wmu[n], wm1 = wmu[16 + n];
    const float bm  = bmu[0];

    const int mB = bg * 16 + n;
    const size_t xrow = (size_t)mB * GN * 2;
    const size_t erow = (size_t)mB * GE * 4;

    char* rr = wbase + n * ROWB;
    char* wr = wbase + (q * 4) * ROWB;
    const f32x4 zero = {0.f, 0.f, 0.f, 0.f};

    const float* eb_ptr = e + erow + (q == 0 ? 0 : q == 1 ? (size_t)(GC - 1) * 4
                                                          : (size_t)(2 * (GC - 1)) * 4);
    const int posoff = (q == 2 ? 1 : 0) - 2;
    const float* xp0 = x + xrow;
    const float* xp1 = x + xrow + (size_t)2 * GC;

    char *rL1[2], *rL2[2], *rL3[3][2], *wH2p[2], *wH3p[2], *cmtE[2], *cmtX[2];
    char *rZ2r[3], *rZ3t[3];
#pragma unroll
    for (int pp = 0; pp < 2; ++pp) {
        rL1[pp] = rr + (q == 0 ? OFF_X + pp * 16
                      : q == 1 ? OFF_X + (pp ^ 1) * 16
                      : q == 2 ? OFF_E + pp * 32
                               : OFF_E + pp * 32 + 16);
        rL2[pp] = rr + (q == 0 ? OFF_H2 + pp * 16
                      : q == 1 ? OFF_H2 + (pp ^ 1) * 16
                      : q == 2 ? OFF_E + pp * 32
                               : OFF_E + pp * 32 + 16);
        wH2p[pp] = wr + OFF_H2 + pp * 16 + n * 2;
        wH3p[pp] = wr + OFF_H3 + pp * 32 + n * 2;
        cmtE[pp] = rr + OFF_E + (pp ^ 1) * 32 + q * 8;   // q<3 lanes
        cmtX[pp] = rr + OFF_X + (pp ^ 1) * 16;           // q==3 lanes
#pragma unroll
        for (int t = 0; t < 3; ++t) {
            const int cp = pp ^ 1;                        // parity of col j-1
            int off;
            if (q == 0)      off = (t == 0) ? OFF_H3 + cp * 32 : OFF_H3 + cp * 32 + 16;
            else if (q == 1) off = (t == 0) ? OFF_H3 + (cp ^ 1) * 32
                             : (t == 1) ? OFF_H3 + (cp ^ 1) * 32 + 16
                                        : OFF_H3 + cp * 32;
            else if (q == 2) off = OFF_E + cp * 32 + t * 8;
            else             off = OFF_E;                 // frag zero at K24-31
            rL3[t][pp] = rr + off;
        }
    }
#pragma unroll
    for (int t = 0; t < 3; ++t) {
        rZ2r[t] = rr + OFF_Z2 + (q == 0 ? t * 16 : 0);    // frag4 zero for K>=8
        rZ3t[t] = rr + ((q < 2) ? OFF_Z3 + t * 32 + q * 16 : OFF_Z3);
    }
    char* wZ1t = wr + OFF_Z1 + (n >> 2) * 16 + (n & 3) * 2;
    char* rZ1  = rr + OFF_Z1;
    char* wZ2n = wr + OFF_Z2 + n * 2;
    char* wZ3  = wr + OFF_Z3 + n * 2;
    char* outw = ldsout + (q * 4 + n) * OUTSTRIDE;

    float4 ck[4];

    // prologue: E(col j0-2) plain -> slot 0; X(j0-3)->slot1, X(j0-2)->slot0 (split)
    if (q < 3) {
        int P = min(max(j0 - 3 + (q == 2 ? 1 : 0), 0), (q == 2 ? GC - 1 : GC - 2));
        float4 ev = *(const float4*)(eb_ptr + 4 * (size_t)P);
        uint2 o2; o2.x = pkf16(ev.x, ev.y); o2.y = pkf16(ev.z, ev.w);
        *(uint2*)(rr + OFF_E + q * 8) = o2;
    } else {
#pragma unroll
        for (int s = 0; s < 2; ++s) {
            int P = min(max(j0 - 3 + s, 0), GC - 1);
            float2 a = *(const float2*)(xp0 + 2 * (size_t)P);
            float2 b = *(const float2*)(xp1 + 2 * (size_t)P);
            uint4 o; o.x = splitpk(a.x); o.y = splitpk(a.y);
            o.z = splitpk(b.x); o.w = splitpk(b.y);
            *(uint4*)(rr + OFF_X + (1 - s) * 16) = o;
        }
    }

    // window 0 (clamped loads)
    if (q < 3) {
#pragma unroll
        for (int cc = 0; cc < 4; ++cc) {
            int P = min(max(j0 + cc + posoff, 0), (q == 2 ? GC - 1 : GC - 2));
            ck[cc] = *(const float4*)(eb_ptr + 4 * (size_t)P);
        }
    } else {
#pragma unroll
        for (int cc = 0; cc < 4; ++cc) {
            int P = min(max(j0 - 1 + cc, 0), GC - 1);
            float2 a = *(const float2*)(xp0 + 2 * (size_t)P);
            float2 b = *(const float2*)(xp1 + 2 * (size_t)P);
            if (cc == 0)      { ck[0].x=a.x; ck[0].y=a.y; ck[2].x=b.x; ck[2].y=b.y; }
            else if (cc == 1) { ck[0].z=a.x; ck[0].w=a.y; ck[2].z=b.x; ck[2].w=b.y; }
            else if (cc == 2) { ck[1].x=a.x; ck[1].y=a.y; ck[3].x=b.x; ck[3].y=b.y; }
            else              { ck[1].z=a.x; ck[1].w=a.y; ck[3].z=b.x; ck[3].w=b.y; }
        }
    }
    BODY(0, 0, 0, true, false, true);
    BODY(1, 1, 0, true, false, true);
    BODY(2, 0, 0, true, false, true);
    BODY(3, 1, 0, true, true,  true);

    // windows 1..7 (clamp-free)
    for (int w = 1; w < 8; ++w) {
        if (q < 3) {
            const float* pe = eb_ptr + 4 * (size_t)(j0 + 4 * w + posoff);
            ck[0] = *(const float4*)(pe);
            ck[1] = *(const float4*)(pe + 4);
            ck[2] = *(const float4*)(pe + 8);
            ck[3] = *(const float4*)(pe + 12);
        } else {
            const float* p0 = xp0 + 2 * (size_t)(j0 + 4 * w - 1);
            const float* p1 = xp1 + 2 * (size_t)(j0 + 4 * w - 1);
            ck[0].x = p0[0]; ck[0].y = p0[1]; ck[0].z = p0[2]; ck[0].w = p0[3];
            ck[1].x = p0[4]; ck[1].y = p0[5]; ck[1].z = p0[6]; ck[1].w = p0[7];
            ck[2].x = p1[0]; ck[2].y = p1[1]; ck[2].z = p1[2]; ck[2].w = p1[3];
            ck[3].x = p1[4]; ck[3].y = p1[5]; ck[3].z = p1[6]; ck[3].w = p1[7];
        }
        BODY(0, 0, w, true, true, true);
        BODY(1, 1, w, true, true, true);
        BODY(2, 0, w, true, true, true);
        BODY(3, 1, w, true, true, true);
    }

    // tail: it = 32, 33 (L1/L2 + L3), it = 34 (L3 only)
    if (q < 3) {
#pragma unroll
        for (int cc = 0; cc < 2; ++cc) {
            int P = min(max(j0 + 32 + cc + posoff, 0), (q == 2 ? GC - 1 : GC - 2));
            ck[cc] = *(const float4*)(eb_ptr + 4 * (size_t)P);
        }
    } else {
#pragma unroll
        for (int cc = 0; cc < 2; ++cc) {
            int P = min(max(j0 + 31 + cc, 0), GC - 1);
            float2 a = *(const float2*)(xp0 + 2 * (size_t)P);
            float2 b = *(const float2*)(xp1 + 2 * (size_t)P);
            if (cc == 0) { ck[0].x=a.x; ck[0].y=a.y; ck[2].x=b.x; ck[2].y=b.y; }
            else         { ck[0].z=a.x; ck[0].w=a.y; ck[2].z=b.x; ck[2].w=b.y; }
        }
    }
    BODY(0, 0, 8, true, true, true);
    BODY(1, 1, 8, true, true, true);
    BODY(2, 0, 8, false, true, false);

    // coalesced out flush
    {
        const int bl = l >> 2, cc = l & 3;
        char* orow = ldsout + bl * OUTSTRIDE + cc * 32;
        float4 v0 = *(const float4*)(orow);
        float4 v1 = *(const float4*)(orow + 16);
        float* ob = out + (size_t)(bg * 16 + bl) * GC + j0 + cc * 8;
        *(float4*)(ob)     = v0;
        *(float4*)(ob + 4) = v1;
    }
}

__global__ __launch_bounds__(256, 4) void gnn_mfma(
    const float* __restrict__ x, const float* __restrict__ e,
    const float* __restrict__ b1a, const float* __restrict__ b1b,
    const float* __restrict__ b2a, const float* __restrict__ b2b,
    const float* __restrict__ b3a, const float* __restrict__ b3b,
    const float* __restrict__ wmu, const float* __restrict__ bmu,
    const uint4* __restrict__ tab, float* __restrict__ out)
{
    __shared__ __align__(16) char smem[4 * 16 * ROWB + 4 * OUTWAVE];
    const int strip = blockIdx.x;
    if (strip == 0)
        mfma_body<true>(x, e, b1a, b1b, b2a, b2b, b3a, b3b, wmu, bmu, tab, out,
                        smem, 0);
    else
        mfma_body<false>(x, e, b1a, b1b, b2a, b2b, b3a, b3b, wmu, bmu, tab, out,
                         smem, strip);
}

extern "C" void kernel_launch(void* const* d_in, const int* in_sizes, int n_in,
                              void* d_out, int out_size, void* d_ws, size_t ws_size,
                              hipStream_t stream) {
    const float* x   = (const float*)d_in[0];
    const float* e   = (const float*)d_in[1];
    const float* w1a = (const float*)d_in[4];
    const float* b1a = (const float*)d_in[5];
    const float* w1b = (const float*)d_in[6];
    const float* b1b = (const float*)d_in[7];
    const float* w2a = (const float*)d_in[8];
    const float* b2a = (const float*)d_in[9];
    const float* w2b = (const float*)d_in[10];
    const float* b2b = (const float*)d_in[11];
    const float* w3a = (const float*)d_in[12];
    const float* b3a = (const float*)d_in[13];
    const float* w3b = (const float*)d_in[14];
    const float* b3b = (const float*)d_in[15];
    const float* wmu = (const float*)d_in[16];
    const float* bmu = (const float*)d_in[17];
    float* out = (float*)d_out;
    uint4* tab = (uint4*)d_ws;   // 7*64*16 = 7168 B

    hipLaunchKernelGGL(build_frags, dim3(2), dim3(256), 0, stream,
                       w1a, w1b, w2a, w2b, w3a, w3b, tab);
    hipLaunchKernelGGL(gnn_mfma, dim3(NSTRIP), dim3(256), 0, stream,
                       x, e, b1a, b1b, b2a, b2b, b3a, b3b, wmu, bmu, tab, out);
}

// Round 21
// 105.547 us; speedup vs baseline: 1.0441x; 1.0441x over previous
//
#include <hip/hip_runtime.h>
#include <cstdint>

#define GC 32768
#define GN (2*GC)
#define GE (3*GC-2)
#define NSTRIP 1024

typedef _Float16 f16x8 __attribute__((ext_vector_type(8)));
typedef float f32x4 __attribute__((ext_vector_type(4)));

// ---- unified G1 weight mapping (R6-R18-proven) ----
__device__ __forceinline__ float g1w(const float* w1, int F, int H, int f, int n) {
    if (n >= 3 * H) return 0.f;
    int t = n / H, h = n % H;
    const float* w = w1 + h * (2 * F + 4);
    if (t == 0) {
        if (f < F) return w[f];
        if (f >= 2*F && f < 3*F) return w[F + f - 2*F];
        if (f >= 4*F && f < 4*F + 4) return w[2*F + f - 4*F];
    } else if (t == 1) {
        if (f >= F && f < 2*F) return w[f - F];
        if (f >= 3*F && f < 4*F) return w[F + f - 3*F];
        if (f >= 4*F + 4 && f < 4*F + 8) return w[2*F + f - (4*F+4)];
    } else {
        if (f < F) return w[F + f];
        if (f >= F && f < 2*F) return w[f - F];
        if (f >= 4*F + 8 && f < 4*F + 12) return w[2*F + f - (4*F+8)];
    }
    return 0.f;
}

__device__ __forceinline__ uint32_t pkf16(float a, float b) {
    unsigned short ua = __builtin_bit_cast(unsigned short, (_Float16)a);
    unsigned short ub = __builtin_bit_cast(unsigned short, (_Float16)b);
    return (uint32_t)ua | ((uint32_t)ub << 16);
}
__device__ __forceinline__ uint32_t splitpk(float v) {
    _Float16 h = (_Float16)v;
    _Float16 lo = (_Float16)(v - (float)h);
    return (uint32_t)__builtin_bit_cast(unsigned short, h) |
           ((uint32_t)__builtin_bit_cast(unsigned short, lo) << 16);
}
template<int CTRL>
__device__ __forceinline__ float dppadd(float v) {
    int s = __builtin_amdgcn_update_dpp(0, __builtin_bit_cast(int, v),
                                        CTRL, 0xF, 0xF, true);
    return v + __builtin_bit_cast(float, s);
}

// 11 fragments.
// 0,1: L1G1 unified split-pair (X,E)    2: L1G2 PLAIN (K 0..3 = w1b[col][0..3])
// 3,5: L2G1 h-chunk PLAIN (K 0..15 = [h0c h1c h0p h1p], nt0/nt1)
// 4,6: L2G1 e-chunk split-pair (features 16..27, nt0/nt1)
// 7:  L2G2 PLAIN   8: L3G1 PLAIN [dst8|src8]   9: L3G1 e split-pair  10: L3G2 PLAIN
__global__ void build_frags(const float* __restrict__ w1a, const float* __restrict__ w1b,
                            const float* __restrict__ w2a, const float* __restrict__ w2b,
                            const float* __restrict__ w3a, const float* __restrict__ w3b,
                            uint4* __restrict__ tab) {
    int tid = blockIdx.x * 256 + threadIdx.x;
    if (tid >= 11 * 64) return;
    int fr = tid >> 6, l = tid & 63;
    int col = l & 15, kq = l >> 4;
    float v[8];
#pragma unroll
    for (int i = 0; i < 8; ++i) {
        int kin = kq * 8 + i;
        int f = kin >> 1;
        float val = 0.f;
        if (fr < 2)        val = g1w(w1a, 2, 4, (fr * 32 + kin) >> 1, col);
        else if (fr == 2)  val = (kin < 4 && col < 4) ? w1b[col * 4 + kin] : 0.f;
        else if (fr < 7)  { int nt = (fr - 3) >> 1, c = (fr - 3) & 1;
                            if (c == 0)
                                val = (kin < 16) ? g1w(w2a, 4, 8, kin, nt * 16 + col) : 0.f;
                            else
                                val = g1w(w2a, 4, 8, (32 + kin) >> 1, nt * 16 + col); }
        else if (fr == 7)  val = (kin < 8 && col < 8) ? w2b[col * 8 + kin] : 0.f;
        else if (fr == 8)  val = (kin < 16) ? w3a[col * 20 + kin] : 0.f;
        else if (fr == 9)  val = (f < 4)  ? w3a[col * 20 + 16 + f] : 0.f;
        else               val = (kin < 16) ? w3b[col * 16 + kin] : 0.f;
        v[i] = val;
    }
    uint4 o;
    o.x = pkf16(v[0], v[1]); o.y = pkf16(v[2], v[3]);
    o.z = pkf16(v[4], v[5]); o.w = pkf16(v[6], v[7]);
    tab[fr * 64 + l] = o;
}

// LDS row layout (bytes):
// E 0..95 (2 parity x 48 split) | X 96..127 (2 parity x 16 split)
// H2 128..175: 2 parity x 16 PLAIN [h0(8)|h1(8)] + zero pad 160..175
// H3 192..271: 2 parity x 32 PLAIN + zero pad @+64
// Z1 272..319: 3 types x 16 PLAIN (f16 at bytes 0..7, 8..15 zero)
// Z2 320..383: 48 PLAIN + 16 zero @+48 | Z3 384..479: 3 x 32 PLAIN
#define OFF_E   0
#define OFF_X   96
#define OFF_H2  128
#define OFF_H3  192
#define OFF_Z1  272
#define OFF_Z2  320
#define OFF_Z3  384
#define ROWB    496
#define OUTSTRIDE 132
#define OUTWAVE   (16*OUTSTRIDE)

__device__ __forceinline__ f32x4 mfma16(uint4 a, uint4 b, f32x4 c) {
    return __builtin_amdgcn_mfma_f32_16x16x32_f16(
        __builtin_bit_cast(f16x8, a), __builtin_bit_cast(f16x8, b), c, 0, 0, 0);
}

#define PR4(r) _Pragma("unroll") for (int r = 0; r < 4; ++r)

// One pipeline step. FIRST=false folds all jpos selects away (1023/1024 blocks).
#define BODY(C, P, W, DO_L12, DO_L3, DO_CMT) do {                                  \
    const int itv = 4*(W) + (C);                                                   \
    if (DO_L3) {                                                                   \
        const bool jp3 = FIRST ? ((j0 + itv - 3) >= 1) : true;                     \
        f32x4 s0 = mfma16(*(const uint4*)rADS[0][(P)^1], BF[8], zero);             \
        s0 = mfma16(*(const uint4*)rAEp[0][P], BF[9], s0);                         \
        f32x4 s1 = mfma16(*(const uint4*)rADS[1][(P)^1], BF[8], zero);             \
        s1 = mfma16(*(const uint4*)rAEp[1][P], BF[9], s1);                         \
        f32x4 s2 = mfma16(*(const uint4*)rADS[2][(P)^1], BF[8], zero);             \
        s2 = mfma16(*(const uint4*)rAEp[2][P], BF[9], s2);                         \
        PR4(r) { *(_Float16*)(wZ3 +  0 + r*ROWB) = (_Float16)fmaxf(s0[r]+zb3,0.f); \
                 *(_Float16*)(wZ3 + 32 + r*ROWB) = (_Float16)fmaxf(s1[r]+zb3,0.f); \
                 *(_Float16*)(wZ3 + 64 + r*ROWB) = (_Float16)fmaxf(s2[r]+zb3,0.f); }\
        f32x4 g0 = mfma16(*(const uint4*)rZ3t[0], BF[10], zero);                   \
        f32x4 g1 = mfma16(*(const uint4*)rZ3t[1], BF[10], zero);                   \
        f32x4 g2 = mfma16(*(const uint4*)rZ3t[2], BF[10], zero);                   \
        float part[4];                                                             \
        PR4(r) { float h0 = jp3 ? g0[r] + cb3 : 0.f;                               \
                 float h1 = (jp3 ? fmaxf(g1[r], g2[r]) : g2[r]) + cb3;             \
                 part[r] = fmaf(h0, wm0, h1 * wm1); }                              \
        PR4(r) { part[r] = dppadd<0xB1>(part[r]);                                  \
                 part[r] = dppadd<0x4E>(part[r]);                                  \
                 part[r] = dppadd<0x141>(part[r]);                                 \
                 part[r] = dppadd<0x140>(part[r]); }                               \
        if (n < 4) {                                                               \
            float v = part[0];                                                     \
            v = (n == 1) ? part[1] : v;                                            \
            v = (n == 2) ? part[2] : v;                                            \
            v = (n == 3) ? part[3] : v;                                            \
            *(float*)(outw + (itv - 3) * 4) = v + bm;                              \
        }                                                                          \
    }                                                                              \
    if (DO_L12) {                                                                  \
        const bool jp = FIRST ? ((j0 + itv - 2) >= 1) : true;                      \
        uint4 a0 = *(const uint4*)rA0p[P];                                         \
        uint4 a1 = *(const uint4*)rA1p[P];                                         \
        f32x4 d1 = mfma16(a0, BF[0], zero); d1 = mfma16(a1, BF[1], d1);            \
        if (n < 12) { PR4(r) *(_Float16*)(wZ1t + r*ROWB) =                         \
                          (_Float16)fmaxf(d1[r] + zb1, 0.f); }                     \
        f32x4 dt0 = mfma16(*(const uint4*)(rZ1 +  0), BF[2], zero);                \
        f32x4 dt1 = mfma16(*(const uint4*)(rZ1 + 16), BF[2], zero);                \
        f32x4 dt2 = mfma16(*(const uint4*)(rZ1 + 32), BF[2], zero);                \
        if (n < 4) { PR4(r) {                                                      \
            float h0 = jp ? dt0[r] + cb1 : 0.f;                                    \
            float h1 = (jp ? fmaxf(dt1[r], dt2[r]) : dt2[r]) + cb1;                \
            *(_Float16*)(wH2p[P] + r*ROWB)     = (_Float16)h0;                     \
            *(_Float16*)(wH2p[P] + 8 + r*ROWB) = (_Float16)h1; } }                 \
        uint4 b0 = *(const uint4*)rB0p[P];                                         \
        uint4 b1 = *(const uint4*)rB1p[P];                                         \
        f32x4 t0 = mfma16(b0, BF[3], zero); t0 = mfma16(b1, BF[4], t0);            \
        f32x4 t1 = mfma16(b0, BF[5], zero); t1 = mfma16(b1, BF[6], t1);            \
        PR4(r) *(_Float16*)(wZ2n + r*ROWB) = (_Float16)fmaxf(t0[r] + zb2, 0.f);    \
        if (n < 8) { PR4(r) *(_Float16*)(wZ2n + 32 + r*ROWB) =                     \
                         (_Float16)fmaxf(t1[r] + zb2, 0.f); }                      \
        f32x4 u0 = mfma16(*(const uint4*)rZ2r[0], BF[7], zero);                    \
        f32x4 u1 = mfma16(*(const uint4*)rZ2r[1], BF[7], zero);                    \
        f32x4 u2 = mfma16(*(const uint4*)rZ2r[2], BF[7], zero);                    \
        if (n < 8) { PR4(r) {                                                      \
            float h0 = jp ? u0[r] + cb2 : 0.f;                                     \
            float h1 = (jp ? fmaxf(u1[r], u2[r]) : u2[r]) + cb2;                   \
            *(_Float16*)(wH3p[P] + r*ROWB)      = (_Float16)h0;                    \
            *(_Float16*)(wH3p[P] + 16 + r*ROWB) = (_Float16)h1; } }                \
    }                                                                              \
    if (DO_CMT) {                                                                  \
        float4 val;                                                                \
        if (q < 3) val = ck[C];                                                    \
        else val = make_float4(                                                    \
            ((C)&1) ? ck[(C)>>1].z     : ck[(C)>>1].x,                             \
            ((C)&1) ? ck[(C)>>1].w     : ck[(C)>>1].y,                             \
            ((C)&1) ? ck[2+((C)>>1)].z : ck[2+((C)>>1)].x,                         \
            ((C)&1) ? ck[2+((C)>>1)].w : ck[2+((C)>>1)].y );                       \
        uint4 o; o.x = splitpk(val.x); o.y = splitpk(val.y);                       \
        o.z = splitpk(val.z); o.w = splitpk(val.w);                                \
        if (q < 3) *(uint4*)cmtpE[P] = o;                                          \
        else       *(uint4*)cmtpX[P] = o;                                          \
    }                                                                              \
} while (0)

template<bool FIRST>
__device__ __forceinline__ void mfma_body(
    const float* __restrict__ x, const float* __restrict__ e,
    const float* __restrict__ b1a, const float* __restrict__ b1b,
    const float* __restrict__ b2a, const float* __restrict__ b2b,
    const float* __restrict__ b3a, const float* __restrict__ b3b,
    const float* __restrict__ wmu, const float* __restrict__ bmu,
    const uint4* __restrict__ tab, float* __restrict__ out,
    char* smem, int strip)
{
    const int l  = threadIdx.x & 63;
    const int wv = threadIdx.x >> 6;
    char* wbase  = smem + wv * 16 * ROWB;
    char* ldsout = smem + 4 * 16 * ROWB + wv * OUTWAVE;

    const int bg = wv;
    const int j0 = strip * 32;

    const int n = l & 15;
    const int q = l >> 4;

    { // zero wave-private compute slice (16 x 496 B = 1984 dwords)
        uint32_t* p = (uint32_t*)wbase;
#pragma unroll
        for (int i = 0; i < 31; ++i) p[l * 31 + i] = 0u;
    }

    uint4 BF[11];
#pragma unroll
    for (int f = 0; f < 11; ++f) BF[f] = tab[f * 64 + l];

    const float zb1 = b1a[n & 3], zb2 = b2a[n & 7], zb3 = b3a[n];
    const float cb1 = b1b[n & 3], cb2 = b2b[n & 7], cb3 = b3b[n];
    const float wm0 = wmu[n], wm1 = wmu[16 + n];
    const float bm  = bmu[0];

    const int mB = bg * 16 + n;
    const size_t xrow = (size_t)mB * GN * 2;
    const size_t erow = (size_t)mB * GE * 4;

    char* rr = wbase + n * ROWB;
    char* wr = wbase + (q * 4) * ROWB;
    const f32x4 zero = {0.f, 0.f, 0.f, 0.f};

    const float* eb_ptr = e + erow + (q == 0 ? 0 : q == 1 ? (size_t)(GC - 1) * 4
                                                          : (size_t)(2 * (GC - 1)) * 4);
    const int posoff = (q == 2 ? 1 : 0) - 2;
    const float* xp0 = x + xrow;
    const float* xp1 = x + xrow + (size_t)2 * GC;

    char *rA0p[2], *rA1p[2], *rB0p[2], *rB1p[2], *wH2p[2], *wH3p[2];
    char *cmtpE[2], *cmtpX[2];
    char *rAEp[3][2], *rADS[3][2], *rZ2r[3], *rZ3t[3];
#pragma unroll
    for (int pp = 0; pp < 2; ++pp) {
        rA0p[pp] = rr + (q == 0 ? OFF_X + pp * 16 : q == 1 ? OFF_X + (pp ^ 1) * 16
                        : q == 2 ? OFF_E + pp * 48 : OFF_E + pp * 48 + 16);
        rA1p[pp] = rr + OFF_E + pp * 48 + (q == 0 ? 32 : 0);
        // L2 h-operand: plain H2. q0 = cur col, q1 = prev col, q>=2 = zero pad
        rB0p[pp] = rr + (q == 0 ? OFF_H2 + pp * 16
                        : q == 1 ? OFF_H2 + (pp ^ 1) * 16 : OFF_H2 + 32);
        rB1p[pp] = rr + OFF_E + pp * 48 + (q == 0 ? 0 : q == 1 ? 16 : q == 2 ? 32 : 0);
        wH2p[pp] = wr + OFF_H2 + pp * 16 + n * 2;
        wH3p[pp] = wr + OFF_H3 + pp * 32 + n * 2;
        cmtpE[pp] = rr + OFF_E + (pp ^ 1) * 48 + q * 16;
        cmtpX[pp] = rr + OFF_X + (pp ^ 1) * 16;
#pragma unroll
        for (int t = 0; t < 3; ++t) {
            rAEp[t][pp] = rr + OFF_E + (pp ^ 1) * 48 + (q == 0 ? t * 16 : 0);
            int offq0 = (t == 0) ? OFF_H3 + pp * 32 : OFF_H3 + pp * 32 + 16;
            int offq1 = (t == 0) ? OFF_H3 + (pp ^ 1) * 32
                      : (t == 1) ? OFF_H3 + (pp ^ 1) * 32 + 16
                                 : OFF_H3 + pp * 32;
            rADS[t][pp] = rr + (q == 0 ? offq0 : q == 1 ? offq1 : OFF_H3 + 64);
        }
    }
#pragma unroll
    for (int t = 0; t < 3; ++t) {
        rZ2r[t] = rr + OFF_Z2 + (q == 0 ? t * 16 : 48);
        rZ3t[t] = (q < 2) ? rr + OFF_Z3 + t * 32 + q * 16 : rr + OFF_H3 + 64;
    }
    char* wZ1t = wr + OFF_Z1 + (n >> 2) * 16 + (n & 3) * 2;   // plain f16 z1
    char* rZ1  = rr + OFF_Z1;
    char* wZ2n = wr + OFF_Z2 + n * 2;
    char* wZ3  = wr + OFF_Z3 + n * 2;
    char* outw = ldsout + (q * 4 + n) * OUTSTRIDE;

    float4 ck[4];

    // prologue: E(col j0-2) -> slot 0; X(j0-3)->slot1, X(j0-2)->slot0
    if (q < 3) {
        int P = min(max(j0 - 3 + (q == 2 ? 1 : 0), 0), (q == 2 ? GC - 1 : GC - 2));
        float4 ev = *(const float4*)(eb_ptr + 4 * (size_t)P);
        uint4 o; o.x = splitpk(ev.x); o.y = splitpk(ev.y);
        o.z = splitpk(ev.z); o.w = splitpk(ev.w);
        *(uint4*)(rr + OFF_E + q * 16) = o;
    } else {
#pragma unroll
        for (int s = 0; s < 2; ++s) {
            int P = min(max(j0 - 3 + s, 0), GC - 1);
            float2 a = *(const float2*)(xp0 + 2 * (size_t)P);
            float2 b = *(const float2*)(xp1 + 2 * (size_t)P);
            uint4 o; o.x = splitpk(a.x); o.y = splitpk(a.y);
            o.z = splitpk(b.x); o.w = splitpk(b.y);
            *(uint4*)(rr + OFF_X + (1 - s) * 16) = o;
        }
    }

    // window 0 (clamped loads)
    if (q < 3) {
#pragma unroll
        for (int cc = 0; cc < 4; ++cc) {
            int P = min(max(j0 + cc + posoff, 0), (q == 2 ? GC - 1 : GC - 2));
            ck[cc] = *(const float4*)(eb_ptr + 4 * (size_t)P);
        }
    } else {
#pragma unroll
        for (int cc = 0; cc < 4; ++cc) {
            int P = min(max(j0 - 1 + cc, 0), GC - 1);
            float2 a = *(const float2*)(xp0 + 2 * (size_t)P);
            float2 b = *(const float2*)(xp1 + 2 * (size_t)P);
            if (cc == 0)      { ck[0].x=a.x; ck[0].y=a.y; ck[2].x=b.x; ck[2].y=b.y; }
            else if (cc == 1) { ck[0].z=a.x; ck[0].w=a.y; ck[2].z=b.x; ck[2].w=b.y; }
            else if (cc == 2) { ck[1].x=a.x; ck[1].y=a.y; ck[3].x=b.x; ck[3].y=b.y; }
            else              { ck[1].z=a.x; ck[1].w=a.y; ck[3].z=b.x; ck[3].w=b.y; }
        }
    }
    BODY(0, 0, 0, true, false, true);
    BODY(1, 1, 0, true, false, true);
    BODY(2, 0, 0, true, false, true);
    BODY(3, 1, 0, true, true,  true);

    // windows 1..7 (clamp-free)
    for (int w = 1; w < 8; ++w) {
        if (q < 3) {
            const float* pe = eb_ptr + 4 * (size_t)(j0 + 4 * w + posoff);
            ck[0] = *(const float4*)(pe);
            ck[1] = *(const float4*)(pe + 4);
            ck[2] = *(const float4*)(pe + 8);
            ck[3] = *(const float4*)(pe + 12);
        } else {
            const float* p0 = xp0 + 2 * (size_t)(j0 + 4 * w - 1);
            const float* p1 = xp1 + 2 * (size_t)(j0 + 4 * w - 1);
            ck[0].x = p0[0]; ck[0].y = p0[1]; ck[0].z = p0[2]; ck[0].w = p0[3];
            ck[1].x = p0[4]; ck[1].y = p0[5]; ck[1].z = p0[6]; ck[1].w = p0[7];
            ck[2].x = p1[0]; ck[2].y = p1[1]; ck[2].z = p1[2]; ck[2].w = p1[3];
            ck[3].x = p1[4]; ck[3].y = p1[5]; ck[3].z = p1[6]; ck[3].w = p1[7];
        }
        BODY(0, 0, w, true, true, true);
        BODY(1, 1, w, true, true, true);
        BODY(2, 0, w, true, true, true);
        BODY(3, 1, w, true, true, true);
    }

    // tail: it = 32, 33 (L1/L2 + L3), it = 34 (L3 only)
    if (q < 3) {
#pragma unroll
        for (int cc = 0; cc < 2; ++cc) {
            int P = min(max(j0 + 32 + cc + posoff, 0), (q == 2 ? GC - 1 : GC - 2));
            ck[cc] = *(const float4*)(eb_ptr + 4 * (size_t)P);
        }
    } else {
#pragma unroll
        for (int cc = 0; cc < 2; ++cc) {
            int P = min(max(j0 + 31 + cc, 0), GC - 1);
            float2 a = *(const float2*)(xp0 + 2 * (size_t)P);
            float2 b = *(const float2*)(xp1 + 2 * (size_t)P);
            if (cc == 0) { ck[0].x=a.x; ck[0].y=a.y; ck[2].x=b.x; ck[2].y=b.y; }
            else         { ck[0].z=a.x; ck[0].w=a.y; ck[2].z=b.x; ck[2].w=b.y; }
        }
    }
    BODY(0, 0, 8, true, true, true);
    BODY(1, 1, 8, true, true, true);
    BODY(2, 0, 8, false, true, false);

    // coalesced out flush
    {
        const int bl = l >> 2, cc = l & 3;
        char* orow = ldsout + bl * OUTSTRIDE + cc * 32;
        float4 v0 = *(const float4*)(orow);
        float4 v1 = *(const float4*)(orow + 16);
        float* ob = out + (size_t)(bg * 16 + bl) * GC + j0 + cc * 8;
        *(float4*)(ob)     = v0;
        *(float4*)(ob + 4) = v1;
    }
}

__global__ __launch_bounds__(256, 4) void gnn_mfma(
    const float* __restrict__ x, const float* __restrict__ e,
    const float* __restrict__ b1a, const float* __restrict__ b1b,
    const float* __restrict__ b2a, const float* __restrict__ b2b,
    const float* __restrict__ b3a, const float* __restrict__ b3b,
    const float* __restrict__ wmu, const float* __restrict__ bmu,
    const uint4* __restrict__ tab, float* __restrict__ out)
{
    __shared__ __align__(16) char smem[4 * 16 * ROWB + 4 * OUTWAVE];
    const int strip = blockIdx.x;
    if (strip == 0)
        mfma_body<true>(x, e, b1a, b1b, b2a, b2b, b3a, b3b, wmu, bmu, tab, out,
                        smem, 0);
    else
        mfma_body<false>(x, e, b1a, b1b, b2a, b2b, b3a, b3b, wmu, bmu, tab, out,
                         smem, strip);
}

extern "C" void kernel_launch(void* const* d_in, const int* in_sizes, int n_in,
                              void* d_out, int out_size, void* d_ws, size_t ws_size,
                              hipStream_t stream) {
    const float* x   = (const float*)d_in[0];
    const float* e   = (const float*)d_in[1];
    const float* w1a = (const float*)d_in[4];
    const float* b1a = (const float*)d_in[5];
    const float* w1b = (const float*)d_in[6];
    const float* b1b = (const float*)d_in[7];
    const float* w2a = (const float*)d_in[8];
    const float* b2a = (const float*)d_in[9];
    const float* w2b = (const float*)d_in[10];
    const float* b2b = (const float*)d_in[11];
    const float* w3a = (const float*)d_in[12];
    const float* b3a = (const float*)d_in[13];
    const float* w3b = (const float*)d_in[14];
    const float* b3b = (const float*)d_in[15];
    const float* wmu = (const float*)d_in[16];
    const float* bmu = (const float*)d_in[17];
    float* out = (float*)d_out;
    uint4* tab = (uint4*)d_ws;   // 11*64*16 = 11264 B

    hipLaunchKernelGGL(build_frags, dim3(3), dim3(256), 0, stream,
                       w1a, w1b, w2a, w2b, w3a, w3b, tab);
    hipLaunchKernelGGL(gnn_mfma, dim3(NSTRIP), dim3(256), 0, stream,
                       x, e, b1a, b1b, b2a, b2b, b3a, b3b, wmu, bmu, tab, out);
}